// Round 18
// baseline (154.604 us; speedup 1.0000x reference)
//
#include <hip/hip_runtime.h>

// k-means cluster step: N=400000, D=256, K=50 (fp32 in/out).
// Round 18 = round 17 with SWAPPED phase-A operands (T12 trick):
//   scores^T = C * X^T  (A-operand = C rows, B-operand = x rows, both b128)
//   -> C/D col(lane&31) = POINT: each lane holds 16 scores of one point,
//      clusters lane-local -> argmin = 15 in-reg compares + shfl_xor(32)
//      + tiny 2-way cross-wave combine (wave 8, interval 2).
//   Deletes: score dump (64 LDS writes), sS0/sS1 (9.2KB), argmin waves'
//   reads/butterflies. Interval-2 pole ~0. Argmin exact f32.
// Rest unchanged from r17: de-pinned (__syncthreads + reg deps), setprio,
// ring-2 f16 staging, phase B = PT^T*X 16x16 MFMA all 16 waves, PT onehot.

typedef _Float16 f16x8 __attribute__((ext_vector_type(8)));
typedef float    f32x4 __attribute__((ext_vector_type(4)));
typedef float    f32x16 __attribute__((ext_vector_type(16)));
typedef unsigned int u32x4 __attribute__((ext_vector_type(4)));

constexpr int K = 50, KP = 64, D = 256, KD = K * D;
constexpr int BLK = 1024, GRID = 512, CH = 32;
constexpr int PST  = 40;   // P^T f16 stride: 80B = 5x16B (uniform bank quads)

__global__ __launch_bounds__(BLK)
void k_fused(const float* __restrict__ x, const float* __restrict__ cc,
             float* __restrict__ partial, float* __restrict__ out,
             int N, int useAtomic) {
    __shared__ _Float16       sC[K * D];        // 25.6 KB, 16B-chunk XOR ^(r&7)
    __shared__ unsigned short sxh[2][CH * D];   // 32 KB f16 ring-2
    __shared__ alignas(16) _Float16 sPT[2][64 * PST]; // 10.2 KB onehot^T ping-pong
    __shared__ float          sc2[KP];          // c2 (INF for k>=50)
    __shared__ float          sAM[2][CH];       // per-wave argmin candidates
    __shared__ int            sAI[2][CH];
    __shared__ int            scnt[K];

    const int tid = threadIdx.x;
    for (int i = tid; i < K * D; i += BLK) sC[i] = (_Float16)0.f;
    for (int i = tid; i < 2 * 64 * PST; i += BLK) sPT[0][i] = (_Float16)0.f;
    if (tid < K) scnt[tid] = 0;
    __syncthreads();
    for (int i = tid; i < KD; i += BLK) {
        int r = i >> 8, col = i & 255, ch = col >> 3, wd = col & 7;
        sC[r * D + (((ch ^ (r & 7)) << 3) | wd)] = (_Float16)cc[i];
    }
    if (tid < KP) {
        float s = 3.4e38f;                      // INF mask for padded clusters
        if (tid < K) {
            s = 0.f;
            for (int q = 0; q < D; ++q) { float v = cc[tid * D + q]; s += v * v; }
        }
        sc2[tid] = s;
    }
    __syncthreads();

    const int lane = tid & 63, ci = lane & 15, g = lane >> 4, w = tid >> 6;
    // phase-A role (waves 14,15): wave = cluster tile wA (cls 0-31 / 32-63)
    const int wA   = w & 1;                   // 14->0, 15->1
    const int pl   = lane & 31;               // point (output col) & operand row
    const int dl   = lane >> 5;               // k-subgroup
    const int xkey = (pl & 7) ^ (((pl >> 3) & 1) << 2);  // key(x row = pl)
    const int cl32 = wA * 32 + pl;            // this lane's C-operand row
    const int clkey = pl & 7;                 // (mismatch on clamped rows is INF-masked)
    const _Float16* cbp = &sC[(cl32 < K ? cl32 : K - 1) * D];  // clamped row
    // phase-B role (all 16 waves): output n-tile w
    const int bcol = w * 16 + ci, bc3 = bcol >> 3, bce = bcol & 7;

    const int nCh = N / CH;
    const int cpb = nCh / gridDim.x, rem = nCh % gridDim.x;
    const int bid = blockIdx.x;
    const int lo  = bid * cpb + (bid < rem ? bid : rem);
    const int cnt = cpb + (bid < rem ? 1 : 0);

    // staging: wave w owns rows 2w,2w+1; lane = row 2w+(l>>5), cols 8c..8c+7
    const int srow = 2 * w + (lane >> 5);
    const int scol = (lane & 31);
    const int skey = (srow & 7) ^ (((srow >> 3) & 1) << 2);
    f32x4 rA = {0,0,0,0}, rB = {0,0,0,0};
#define ISSUE(t_) { const float* b_ = x + (size_t)(t_) * (CH * D) + srow * D + 8 * scol; \
    rA = *(const f32x4*)(b_); rB = *(const f32x4*)(b_ + 4); }
#define WSLOT(s_) { \
    f16x8 h_ = {(_Float16)rA[0], (_Float16)rA[1], (_Float16)rA[2], (_Float16)rA[3], \
                (_Float16)rB[0], (_Float16)rB[1], (_Float16)rB[2], (_Float16)rB[3]}; \
    *(f16x8*)(&sxh[s_][srow * D + ((scol ^ skey) << 3)]) = h_; }

    f32x4 bacc0 = {0,0,0,0}, bacc1 = {0,0,0,0}, bacc2 = {0,0,0,0}, bacc3 = {0,0,0,0};

    // prologue: slot0 <- chunk lo (reg-dep wait auto-inserted); issue lo+1
    if (cnt > 0) { ISSUE(lo) WSLOT(0) if (cnt > 1) ISSUE(lo + 1) }
    __syncthreads();

    for (int i = 0; i <= cnt; ++i) {
        // -------- interval 1: B(i-1) first (short chain), then A(i) --------
        if (i >= 1) {                    // phase B: scatter chunk i-1, all waves
            const unsigned short* xbh = &sxh[(i - 1) & 1][0];
            const _Float16* pt = &sPT[(i - 1) & 1][0];
            unsigned short v0, v1, v2, v3, v4, v5, v6, v7;
#define RDH(j) { const int p_ = 8 * g + (j); const int key_ = (j) ^ ((g & 1) << 2); \
            v##j = xbh[p_ * D + ((bc3 ^ key_) << 3) + bce]; }
            RDH(0) RDH(1) RDH(2) RDH(3) RDH(4) RDH(5) RDH(6) RDH(7)
#undef RDH
            unsigned int w0 = (unsigned int)v0 | ((unsigned int)v1 << 16);
            unsigned int w1 = (unsigned int)v2 | ((unsigned int)v3 << 16);
            unsigned int w2 = (unsigned int)v4 | ((unsigned int)v5 << 16);
            unsigned int w3 = (unsigned int)v6 | ((unsigned int)v7 << 16);
            u32x4 W = {w0, w1, w2, w3};
            f16x8 bfr = __builtin_bit_cast(f16x8, W);
            __builtin_amdgcn_s_setprio(1);
#define BMT(M, ACC) { \
            f16x8 a = *(const f16x8*)(pt + ((M) * 16 + ci) * PST + 8 * g); \
            ACC = __builtin_amdgcn_mfma_f32_16x16x32_f16(a, bfr, ACC, 0, 0, 0); }
            BMT(0, bacc0) BMT(1, bacc1) BMT(2, bacc2) BMT(3, bacc3)
#undef BMT
            __builtin_amdgcn_s_setprio(0);
        }

        if (w >= 14 && i < cnt) {        // phase A: scores^T = C * X^T
            const unsigned short* xb = &sxh[i & 1][0];
            f32x16 acc = {0,0,0,0,0,0,0,0,0,0,0,0,0,0,0,0};
            __builtin_amdgcn_s_setprio(1);
#define A_KS(ks) { \
            const int c_ = (ks) * 2 + dl; \
            f16x8 a = *(const f16x8*)(cbp + ((c_ ^ clkey) << 3));          /* C row  */ \
            f16x8 b = *(const f16x8*)(&xb[pl * D + ((c_ ^ xkey) << 3)]);   /* x row  */ \
            acc = __builtin_amdgcn_mfma_f32_32x32x16_f16(a, b, acc, 0, 0, 0); }
            A_KS(0) A_KS(1) A_KS(2) A_KS(3) A_KS(4) A_KS(5) A_KS(6) A_KS(7)
            A_KS(8) A_KS(9) A_KS(10) A_KS(11) A_KS(12) A_KS(13) A_KS(14) A_KS(15)
#undef A_KS
            __builtin_amdgcn_s_setprio(0);
            // lane holds score[cluster=32wA+4dl+8q+j][point=pl] in acc[4q+j].
            // c2 for those clusters: 4x f32x4 from sc2 (INF-masked pads).
            float bm = 3.4e38f; int bb = 0;
#define AQ(q) { \
            f32x4 c2q = *(const f32x4*)(&sc2[32 * wA + 4 * dl + 8 * (q)]); \
            { float s_ = c2q[0] - 2.f * acc[4*(q)+0]; int c_ = 32*wA + 4*dl + 8*(q) + 0; \
              if (s_ < bm || (s_ == bm && c_ < bb)) { bm = s_; bb = c_; } } \
            { float s_ = c2q[1] - 2.f * acc[4*(q)+1]; int c_ = 32*wA + 4*dl + 8*(q) + 1; \
              if (s_ < bm || (s_ == bm && c_ < bb)) { bm = s_; bb = c_; } } \
            { float s_ = c2q[2] - 2.f * acc[4*(q)+2]; int c_ = 32*wA + 4*dl + 8*(q) + 2; \
              if (s_ < bm || (s_ == bm && c_ < bb)) { bm = s_; bb = c_; } } \
            { float s_ = c2q[3] - 2.f * acc[4*(q)+3]; int c_ = 32*wA + 4*dl + 8*(q) + 3; \
              if (s_ < bm || (s_ == bm && c_ < bb)) { bm = s_; bb = c_; } } }
            AQ(0) AQ(1) AQ(2) AQ(3)
#undef AQ
            // combine dl halves (lanes l and l^32 share point pl)
            { float pm = __shfl_xor(bm, 32, 64); int pb = __shfl_xor(bb, 32, 64);
              if (pm < bm || (pm == bm && pb < bb)) { bm = pm; bb = pb; } }
            if (lane < 32) { sAM[wA][pl] = bm; sAI[wA][pl] = bb; }
        }

        __syncthreads();   // candidates(i) visible; slot/PT (i-1)&1 reads retired

        // ---- interval 2: WSLOT(i+1); ISSUE(i+2); zero PT; combine -> PT(i) ----
        if (i + 1 < cnt) {
            WSLOT((i + 1) & 1)            // waits ISSUE(i+1) via reg dep only
            if (i + 2 < cnt) ISSUE(lo + i + 2)
        }

        if (w < 8 && i + 1 < cnt) {      // zero PT((i+1)&1): 320 b128 writes
            const int z = w * 64 + lane;
            if (z < (64 * PST * 2) / 16) {
                f16x8 zz = {(_Float16)0.f,(_Float16)0.f,(_Float16)0.f,(_Float16)0.f,
                            (_Float16)0.f,(_Float16)0.f,(_Float16)0.f,(_Float16)0.f};
                *(f16x8*)(&sPT[(i + 1) & 1][z * 8]) = zz;
            }
        }

        if (w == 8 && lane < 32 && i < cnt) {   // cross-wave argmin combine
            float m0 = sAM[0][lane], m1 = sAM[1][lane];
            int   b0 = sAI[0][lane], b1 = sAI[1][lane];
            const int best = (m1 < m0 || (m1 == m0 && b1 < b0)) ? b1 : b0;
            sPT[i & 1][best * PST + lane] = (_Float16)1.f;
            atomicAdd(&scnt[best], 1);
        }
        __syncthreads();   // slot(i+1), PT zero/ones visible for next iter
    }

    // ---- writeback: D row = M*16+4g+r (cluster), col = bcol ----
    if (useAtomic) {
#define WBK(M, ACC) { \
        { int cl_ = (M)*16 + 4*g + 0; if (cl_ < K) atomicAdd(&out[cl_ * D + bcol], ACC[0]); } \
        { int cl_ = (M)*16 + 4*g + 1; if (cl_ < K) atomicAdd(&out[cl_ * D + bcol], ACC[1]); } \
        { int cl_ = (M)*16 + 4*g + 2; if (cl_ < K) atomicAdd(&out[cl_ * D + bcol], ACC[2]); } \
        { int cl_ = (M)*16 + 4*g + 3; if (cl_ < K) atomicAdd(&out[cl_ * D + bcol], ACC[3]); } }
        WBK(0, bacc0) WBK(1, bacc1) WBK(2, bacc2) WBK(3, bacc3)
#undef WBK
    } else {
        float* pb = partial + (size_t)bid * KD;
#define WBK(M, ACC) { \
        { int cl_ = (M)*16 + 4*g + 0; if (cl_ < K) pb[cl_ * D + bcol] = ACC[0]; } \
        { int cl_ = (M)*16 + 4*g + 1; if (cl_ < K) pb[cl_ * D + bcol] = ACC[1]; } \
        { int cl_ = (M)*16 + 4*g + 2; if (cl_ < K) pb[cl_ * D + bcol] = ACC[2]; } \
        { int cl_ = (M)*16 + 4*g + 3; if (cl_ < K) pb[cl_ * D + bcol] = ACC[3]; } }
        WBK(0, bacc0) WBK(1, bacc1) WBK(2, bacc2) WBK(3, bacc3)
#undef WBK
    }
    __syncthreads();
    for (int k = tid; k < K; k += BLK) atomicAdd(&out[KD + k], (float)scnt[k]);
}

// partial reduction: 8 slices of 64 partials, atomicAdd into zeroed out
__global__ __launch_bounds__(256)
void k_reduce(const float* __restrict__ partial, float* __restrict__ out, int G) {
    const int j  = blockIdx.x * 256 + threadIdx.x;    // < KD
    const int bs = G / 8;
    const int b0 = blockIdx.y * bs;
    float s = 0.f;
    for (int b = b0; b < b0 + bs; ++b) s += partial[(size_t)b * KD + j];
    atomicAdd(&out[j], s);
}

extern "C" void kernel_launch(void* const* d_in, const int* in_sizes, int n_in,
                              void* d_out, int out_size, void* d_ws, size_t ws_size,
                              hipStream_t stream) {
    const float* x = (const float*)d_in[0];
    const float* c = (const float*)d_in[1];
    float* out = (float*)d_out;
    const int N = in_sizes[0] / D;

    float* partial = (float*)d_ws;
    const size_t need = (size_t)GRID * KD * sizeof(float);
    const int useAtomic = (ws_size < need) ? 1 : 0;

    hipMemsetAsync(d_out, 0, (size_t)out_size * sizeof(float), stream);
    k_fused<<<GRID, BLK, 0, stream>>>(x, c, partial, out, N, useAtomic);
    if (!useAtomic) {
        k_reduce<<<dim3(KD / 256, 8), 256, 0, stream>>>(partial, out, GRID);
    }
}

// Round 19
// 134.163 us; speedup vs baseline: 1.1524x; 1.1524x over previous
//
#include <hip/hip_runtime.h>

// k-means cluster step: N=400000, D=256, K=50 (fp32 in/out).
// Round 19 = REVERT to round 17 (session best: 133.5us, absmax 64).
// Round 18's swapped-operand phase A regressed +16%: it shrank phase A to
// 2 waves x 16-deep chained MFMA (r15 proved 4x8-deep better) and moved
// argmin onto the A-waves' interval-1 critical path. Reverting.
// All remaining forward levers are blocked by hard walls (audited r19):
//   - any +16 VGPR rebalance > 64-VGPR budget @ 32 waves/CU (spill);
//   - any +LDS restructure > 80KB @ 2 blocks/CU (occupancy halves, r12);
//   - 1-barrier pipeline needs ring-4 staging (LDS-blocked).
// Structure: ring-2 f16 staging; phase A = X*C^T 32x32 MFMA waves 12-15
// (K-halves); phase B = PT^T*X 16x16 MFMA all 16 waves; argmin waves 8-11;
// PT onehot in LDS; de-pinned scheduling + setprio; 2 barriers/chunk.

typedef _Float16 f16x8 __attribute__((ext_vector_type(8)));
typedef float    f32x4 __attribute__((ext_vector_type(4)));
typedef float    f32x16 __attribute__((ext_vector_type(16)));
typedef unsigned int u32x4 __attribute__((ext_vector_type(4)));

constexpr int K = 50, KP = 64, D = 256, KD = K * D;
constexpr int BLK = 1024, GRID = 512, CH = 32;
constexpr int SSTH = 72;   // f16 score stride: 144B rows, 16B-aligned
constexpr int PST  = 40;   // P^T f16 stride: 80B = 5x16B (uniform bank quads)

__global__ __launch_bounds__(BLK)
void k_fused(const float* __restrict__ x, const float* __restrict__ cc,
             float* __restrict__ partial, float* __restrict__ out,
             int N, int useAtomic) {
    __shared__ _Float16       sC[K * D];        // 25.6 KB, 16B-chunk XOR ^(r&7)
    __shared__ unsigned short sxh[2][CH * D];   // 32 KB f16 ring-2
    __shared__ alignas(16) _Float16 sS0[32 * SSTH];  // 4.6 KB f16 scores, half 0 (+c2)
    __shared__ alignas(16) _Float16 sS1[32 * SSTH];  // 4.6 KB f16 scores, half 1
    __shared__ alignas(16) _Float16 sPT[2][64 * PST]; // 10.2 KB onehot^T ping-pong
    __shared__ float          sc2[KP];
    __shared__ int            scnt[K];

    const int tid = threadIdx.x;
    for (int i = tid; i < K * D; i += BLK) sC[i] = (_Float16)0.f;
    for (int i = tid; i < 2 * 64 * PST; i += BLK) sPT[0][i] = (_Float16)0.f;
    if (tid < K) scnt[tid] = 0;
    __syncthreads();
    for (int i = tid; i < KD; i += BLK) {
        int r = i >> 8, col = i & 255, ch = col >> 3, wd = col & 7;
        sC[r * D + (((ch ^ (r & 7)) << 3) | wd)] = (_Float16)cc[i];
    }
    if (tid < KP) {
        float s = 0.f;
        if (tid < K) for (int q = 0; q < D; ++q) { float v = cc[tid * D + q]; s += v * v; }
        sc2[tid] = s;
    }
    __syncthreads();

    const int lane = tid & 63, ci = lane & 15, g = lane >> 4, w = tid >> 6;
    // phase-A role (waves 12-15): kh = K-half, wA = cluster tile (0/1)
    const int kh   = (w >= 14) ? 1 : 0;
    const int wA   = w & 1;
    const int ra   = lane & 31;               // point row
    const int dl   = lane >> 5;               // k-subgroup
    const int rakey = (ra & 7) ^ (((ra >> 3) & 1) << 2);
    const int cl32 = wA * 32 + (lane & 31);   // cluster col (0..63)
    const int clkey = (lane & 31) & 7;
    const _Float16* cbp = &sC[(cl32 < K ? cl32 : K - 1) * D];  // clamped row
    // phase-B role (all 16 waves): output n-tile w
    const int bcol = w * 16 + ci, bc3 = bcol >> 3, bce = bcol & 7;

    const int nCh = N / CH;
    const int cpb = nCh / gridDim.x, rem = nCh % gridDim.x;
    const int bid = blockIdx.x;
    const int lo  = bid * cpb + (bid < rem ? bid : rem);
    const int cnt = cpb + (bid < rem ? 1 : 0);

    const float INF = 3.4e38f;
    const float c2A = (cl32 < K) ? sc2[cl32] : INF;

    // staging: wave w owns rows 2w,2w+1; lane = row 2w+(l>>5), cols 8c..8c+7
    const int srow = 2 * w + (lane >> 5);
    const int scol = (lane & 31);
    const int skey = (srow & 7) ^ (((srow >> 3) & 1) << 2);
    f32x4 rA = {0,0,0,0}, rB = {0,0,0,0};
#define ISSUE(t_) { const float* b_ = x + (size_t)(t_) * (CH * D) + srow * D + 8 * scol; \
    rA = *(const f32x4*)(b_); rB = *(const f32x4*)(b_ + 4); }
#define WSLOT(s_) { \
    f16x8 h_ = {(_Float16)rA[0], (_Float16)rA[1], (_Float16)rA[2], (_Float16)rA[3], \
                (_Float16)rB[0], (_Float16)rB[1], (_Float16)rB[2], (_Float16)rB[3]}; \
    *(f16x8*)(&sxh[s_][srow * D + ((scol ^ skey) << 3)]) = h_; }

    f32x4 bacc0 = {0,0,0,0}, bacc1 = {0,0,0,0}, bacc2 = {0,0,0,0}, bacc3 = {0,0,0,0};

    // prologue: slot0 <- chunk lo (reg-dep wait auto-inserted); issue lo+1
    if (cnt > 0) { ISSUE(lo) WSLOT(0) if (cnt > 1) ISSUE(lo + 1) }
    __syncthreads();

    for (int i = 0; i <= cnt; ++i) {
        // -------- interval 1: B(i-1) first (short chain), then A(i) --------
        if (i >= 1) {                    // phase B: scatter chunk i-1, all waves
            const unsigned short* xbh = &sxh[(i - 1) & 1][0];
            const _Float16* pt = &sPT[(i - 1) & 1][0];
            unsigned short v0, v1, v2, v3, v4, v5, v6, v7;
#define RDH(j) { const int p_ = 8 * g + (j); const int key_ = (j) ^ ((g & 1) << 2); \
            v##j = xbh[p_ * D + ((bc3 ^ key_) << 3) + bce]; }
            RDH(0) RDH(1) RDH(2) RDH(3) RDH(4) RDH(5) RDH(6) RDH(7)
#undef RDH
            unsigned int w0 = (unsigned int)v0 | ((unsigned int)v1 << 16);
            unsigned int w1 = (unsigned int)v2 | ((unsigned int)v3 << 16);
            unsigned int w2 = (unsigned int)v4 | ((unsigned int)v5 << 16);
            unsigned int w3 = (unsigned int)v6 | ((unsigned int)v7 << 16);
            u32x4 W = {w0, w1, w2, w3};
            f16x8 bfr = __builtin_bit_cast(f16x8, W);
            __builtin_amdgcn_s_setprio(1);
#define BMT(M, ACC) { \
            f16x8 a = *(const f16x8*)(pt + ((M) * 16 + ci) * PST + 8 * g); \
            ACC = __builtin_amdgcn_mfma_f32_16x16x32_f16(a, bfr, ACC, 0, 0, 0); }
            BMT(0, bacc0) BMT(1, bacc1) BMT(2, bacc2) BMT(3, bacc3)
#undef BMT
            __builtin_amdgcn_s_setprio(0);
        }

        if (w >= 12 && i < cnt) {        // phase A: 32x32 MFMA, waves 12-15
            const unsigned short* xb = &sxh[i & 1][0];
            f32x16 acc = {0,0,0,0,0,0,0,0,0,0,0,0,0,0,0,0};
            __builtin_amdgcn_s_setprio(1);
#define A_KS(s) { \
            const int c_ = (kh * 8 + (s)) * 2 + dl; \
            f16x8 a = *(const f16x8*)(&xb[ra * D + ((c_ ^ rakey) << 3)]); \
            f16x8 b = *(const f16x8*)(cbp + ((c_ ^ clkey) << 3)); \
            acc = __builtin_amdgcn_mfma_f32_32x32x16_f16(a, b, acc, 0, 0, 0); }
            A_KS(0) A_KS(1) A_KS(2) A_KS(3) A_KS(4) A_KS(5) A_KS(6) A_KS(7)
#undef A_KS
            __builtin_amdgcn_s_setprio(0);
            if (kh == 0) {
#define DUMP(r) { const int row_ = ((r) & 3) + 8 * ((r) >> 2) + 4 * dl; \
                sS0[row_ * SSTH + cl32] = (_Float16)(c2A - 2.f * acc[r]); }
                DUMP(0) DUMP(1) DUMP(2) DUMP(3) DUMP(4) DUMP(5) DUMP(6) DUMP(7)
                DUMP(8) DUMP(9) DUMP(10) DUMP(11) DUMP(12) DUMP(13) DUMP(14) DUMP(15)
#undef DUMP
            } else {
#define DUMP(r) { const int row_ = ((r) & 3) + 8 * ((r) >> 2) + 4 * dl; \
                sS1[row_ * SSTH + cl32] = (_Float16)(-2.f * acc[r]); }
                DUMP(0) DUMP(1) DUMP(2) DUMP(3) DUMP(4) DUMP(5) DUMP(6) DUMP(7)
                DUMP(8) DUMP(9) DUMP(10) DUMP(11) DUMP(12) DUMP(13) DUMP(14) DUMP(15)
#undef DUMP
            }
        }

        __syncthreads();   // scores(i) visible; slot/PT (i-1)&1 reads retired

        // ---- interval 2: WSLOT(i+1); ISSUE(i+2); zero PT(i+1); argmin(i) ----
        if (i + 1 < cnt) {
            WSLOT((i + 1) & 1)            // waits ISSUE(i+1) via reg dep only
            if (i + 2 < cnt) ISSUE(lo + i + 2)
        }

        if (w < 8 && i + 1 < cnt) {      // zero PT((i+1)&1): 320 b128 writes
            const int z = w * 64 + lane;
            if (z < (64 * PST * 2) / 16) {
                f16x8 zz = {(_Float16)0.f,(_Float16)0.f,(_Float16)0.f,(_Float16)0.f,
                            (_Float16)0.f,(_Float16)0.f,(_Float16)0.f,(_Float16)0.f};
                *(f16x8*)(&sPT[(i + 1) & 1][z * 8]) = zz;
            }
        }

        if (w >= 8 && w < 12 && i < cnt) {   // argmin chunk i, waves 8-11
            const int p_ = (w - 8) * 8 + (lane >> 3);   // point 0..31
            const int q  = lane & 7;                     // col octet
            const _Float16* s0p = &sS0[p_ * SSTH + 8 * q];
            const _Float16* s1p = &sS1[p_ * SSTH + 8 * q];
            f16x8 h0 = *(const f16x8*)(s0p);
            f16x8 h1 = *(const f16x8*)(s1p);
            float bm = (float)h0[0] + (float)h1[0]; int bb = 8 * q;
#define CMP(E) { float s_ = (float)h0[E] + (float)h1[E]; int c_ = 8 * q + (E); \
            if (s_ < bm) { bm = s_; bb = c_; } }
            CMP(1) CMP(2) CMP(3) CMP(4) CMP(5) CMP(6) CMP(7)
#undef CMP
            { float pm = __shfl_xor(bm, 1, 64); int pb = __shfl_xor(bb, 1, 64);
              if (pm < bm || (pm == bm && pb < bb)) { bm = pm; bb = pb; } }
            { float pm = __shfl_xor(bm, 2, 64); int pb = __shfl_xor(bb, 2, 64);
              if (pm < bm || (pm == bm && pb < bb)) { bm = pm; bb = pb; } }
            { float pm = __shfl_xor(bm, 4, 64); int pb = __shfl_xor(bb, 4, 64);
              if (pm < bm || (pm == bm && pb < bb)) { bm = pm; bb = pb; } }
            if (q == 0) {
                sPT[i & 1][bb * PST + p_] = (_Float16)1.f;   // one-write
                atomicAdd(&scnt[bb], 1);
            }
        }
        __syncthreads();   // slot(i+1), PT zero/ones visible for next iter
    }

    // ---- writeback: D row = M*16+4g+r (cluster), col = bcol ----
    if (useAtomic) {
#define WBK(M, ACC) { \
        { int cl_ = (M)*16 + 4*g + 0; if (cl_ < K) atomicAdd(&out[cl_ * D + bcol], ACC[0]); } \
        { int cl_ = (M)*16 + 4*g + 1; if (cl_ < K) atomicAdd(&out[cl_ * D + bcol], ACC[1]); } \
        { int cl_ = (M)*16 + 4*g + 2; if (cl_ < K) atomicAdd(&out[cl_ * D + bcol], ACC[2]); } \
        { int cl_ = (M)*16 + 4*g + 3; if (cl_ < K) atomicAdd(&out[cl_ * D + bcol], ACC[3]); } }
        WBK(0, bacc0) WBK(1, bacc1) WBK(2, bacc2) WBK(3, bacc3)
#undef WBK
    } else {
        float* pb = partial + (size_t)bid * KD;
#define WBK(M, ACC) { \
        { int cl_ = (M)*16 + 4*g + 0; if (cl_ < K) pb[cl_ * D + bcol] = ACC[0]; } \
        { int cl_ = (M)*16 + 4*g + 1; if (cl_ < K) pb[cl_ * D + bcol] = ACC[1]; } \
        { int cl_ = (M)*16 + 4*g + 2; if (cl_ < K) pb[cl_ * D + bcol] = ACC[2]; } \
        { int cl_ = (M)*16 + 4*g + 3; if (cl_ < K) pb[cl_ * D + bcol] = ACC[3]; } }
        WBK(0, bacc0) WBK(1, bacc1) WBK(2, bacc2) WBK(3, bacc3)
#undef WBK
    }
    __syncthreads();
    for (int k = tid; k < K; k += BLK) atomicAdd(&out[KD + k], (float)scnt[k]);
}

// partial reduction: 8 slices of 64 partials, atomicAdd into zeroed out
__global__ __launch_bounds__(256)
void k_reduce(const float* __restrict__ partial, float* __restrict__ out, int G) {
    const int j  = blockIdx.x * 256 + threadIdx.x;    // < KD
    const int bs = G / 8;
    const int b0 = blockIdx.y * bs;
    float s = 0.f;
    for (int b = b0; b < b0 + bs; ++b) s += partial[(size_t)b * KD + j];
    atomicAdd(&out[j], s);
}

extern "C" void kernel_launch(void* const* d_in, const int* in_sizes, int n_in,
                              void* d_out, int out_size, void* d_ws, size_t ws_size,
                              hipStream_t stream) {
    const float* x = (const float*)d_in[0];
    const float* c = (const float*)d_in[1];
    float* out = (float*)d_out;
    const int N = in_sizes[0] / D;

    float* partial = (float*)d_ws;
    const size_t need = (size_t)GRID * KD * sizeof(float);
    const int useAtomic = (ws_size < need) ? 1 : 0;

    hipMemsetAsync(d_out, 0, (size_t)out_size * sizeof(float), stream);
    k_fused<<<GRID, BLK, 0, stream>>>(x, c, partial, out, N, useAtomic);
    if (!useAtomic) {
        k_reduce<<<dim3(KD / 256, 8), 256, 0, stream>>>(partial, out, GRID);
    }
}